// Round 3
// baseline (38519.724 us; speedup 1.0000x reference)
//
#include <hip/hip_runtime.h>
#include <hip/hip_fp16.h>
#include <math.h>

namespace {
constexpr int Bn  = 512;
constexpr int Tn  = 100;
constexpr int Hn  = 256;
constexpr int En  = 256;
constexpr int D2n = 512;
constexpr int G4n = 1024;
constexpr float PENf = 1e6f;
constexpr int KT = 16;
constexpr size_t BIGN = (size_t)Bn * Tn * D2n;   // 26,214,400 elements
constexpr size_t SMALL_BYTES =
    ((size_t)2 * Bn * G4n + 5 * Bn * D2n + 3 * Bn * Tn + 4 * Bn * Hn + 4 * G4n) * 4;
constexpr size_t GEMM_SMEM = (size_t)2 * KT * 68 * sizeof(float);
}

// ---- type conversion helpers ----------------------------------------------
template<typename T> __device__ __forceinline__ float cvt_to_f(T x);
template<> __device__ __forceinline__ float cvt_to_f<float>(float x) { return x; }
template<> __device__ __forceinline__ float cvt_to_f<__half>(__half x) {
  return __half2float(x);
}

template<typename T> __device__ __forceinline__ T cvt_from_f(float x);
template<> __device__ __forceinline__ float cvt_from_f<float>(float x) { return x; }
template<> __device__ __forceinline__ __half cvt_from_f<__half>(float x) {
  return __float2half(x);   // round-to-nearest-even
}

__device__ __forceinline__ float h2f_bits(unsigned short b) {
  __half_raw r; r.x = b; return __half2float(__half(r));
}

template<typename T> __device__ __forceinline__ float4 load4(const T* p);
template<> __device__ __forceinline__ float4 load4<float>(const float* p) {
  return *(const float4*)p;
}
template<> __device__ __forceinline__ float4 load4<__half>(const __half* p) {
  const ushort4 u = *(const ushort4*)p;   // 8B-aligned at all call sites
  float4 r;
  r.x = h2f_bits(u.x); r.y = h2f_bits(u.y);
  r.z = h2f_bits(u.z); r.w = h2f_bits(u.w);
  return r;
}

__device__ __forceinline__ float sigmoidf(float x) {
  return 1.0f / (1.0f + expf(-x));
}

// ---------------------------------------------------------------------------
// Generic GEMM body: C[m,n] (+)= bias[n] + sum_k A1[m,k]B1[n,k] + sum_k A2[m,k]B2[n,k]
// A/B/bias fp32; C stored as CT. M,N multiples of 64.
// ---------------------------------------------------------------------------
template<typename CT>
struct GemmSetT {
  const float* A1; const float* B1; int K1; int lda1; int ldb1;
  const float* A2; const float* B2; int K2; int lda2; int ldb2;
  const float* bias; CT* C; int ldc; int acc;
};

template<typename CT>
__device__ __forceinline__ void gemm_body(const GemmSetT<CT>& g,
                                          int m0, int n0, int tx, int ty) {
  extern __shared__ float smem[];
  float* As = smem;                 // [KT][68]
  float* Bs = smem + KT * 68;       // [KT][68]
  float acc[4][4] = {};
  for (int seg = 0; seg < 2; ++seg) {
    const float* A  = seg ? g.A2 : g.A1;
    const float* Bm = seg ? g.B2 : g.B1;
    const int K   = seg ? g.K2 : g.K1;
    const int lda = seg ? g.lda2 : g.lda1;
    const int ldb = seg ? g.ldb2 : g.ldb1;
    if (K <= 0) continue;
    for (int k0 = 0; k0 < K; k0 += KT) {
      const int gk = k0 + tx;
      const bool kin = gk < K;
#pragma unroll
      for (int i = 0; i < 4; ++i) {
        const int r = ty + i * 16;
        As[tx * 68 + r] = kin ? A[(size_t)(m0 + r) * lda + gk] : 0.f;
        Bs[tx * 68 + r] = kin ? Bm[(size_t)(n0 + r) * ldb + gk] : 0.f;
      }
      __syncthreads();
#pragma unroll
      for (int k = 0; k < KT; ++k) {
        const float4 av = *(const float4*)&As[k * 68 + (ty << 2)];
        const float4 bv = *(const float4*)&Bs[k * 68 + (tx << 2)];
        const float a[4] = {av.x, av.y, av.z, av.w};
        const float b[4] = {bv.x, bv.y, bv.z, bv.w};
#pragma unroll
        for (int i = 0; i < 4; ++i)
#pragma unroll
          for (int j = 0; j < 4; ++j)
            acc[i][j] = fmaf(a[i], b[j], acc[i][j]);
      }
      __syncthreads();
    }
  }
#pragma unroll
  for (int i = 0; i < 4; ++i) {
    const int m = m0 + (ty << 2) + i;
    float o[4] = {acc[i][0], acc[i][1], acc[i][2], acc[i][3]};
    if (g.bias) {
      const float4 bb = *(const float4*)&g.bias[n0 + (tx << 2)];
      o[0] += bb.x; o[1] += bb.y; o[2] += bb.z; o[3] += bb.w;
    }
    CT* cp = &g.C[(size_t)m * g.ldc + n0 + (tx << 2)];
    if (g.acc) {
#pragma unroll
      for (int j = 0; j < 4; ++j) o[j] += cvt_to_f<CT>(cp[j]);
    }
#pragma unroll
    for (int j = 0; j < 4; ++j) cp[j] = cvt_from_f<CT>(o[j]);
  }
}

template<typename CT>
__global__ __launch_bounds__(256) void gemm2_kernel(GemmSetT<CT> s0, GemmSetT<CT> s1) {
  gemm_body<CT>(blockIdx.z ? s1 : s0, blockIdx.y * 64, blockIdx.x * 64,
                threadIdx.x & 15, threadIdx.x >> 4);
}

// 4 sets: 0,1 write CT1 (ref1 halves), 2,3 write CT2 (ref2 halves)
template<typename CT1, typename CT2>
__global__ __launch_bounds__(256) void gemm4_kernel(GemmSetT<CT1> s0, GemmSetT<CT1> s1,
                                                    GemmSetT<CT2> s2, GemmSetT<CT2> s3) {
  const int m0 = blockIdx.y * 64, n0 = blockIdx.x * 64;
  const int tx = threadIdx.x & 15, ty = threadIdx.x >> 4;
  if (blockIdx.z < 2) gemm_body<CT1>(blockIdx.z ? s1 : s0, m0, n0, tx, ty);
  else                gemm_body<CT2>(blockIdx.z == 3 ? s3 : s2, m0, n0, tx, ty);
}

// ---------------------------------------------------------------------------
// Weff = Wih @ W_embed : [1024,2] per direction
__global__ void weff_kernel(const float* Wih_f, const float* Wih_b,
                            const float* W_embed, float* weff_f, float* weff_b) {
  const int gidx = blockIdx.x * 256 + threadIdx.x;
  if (gidx >= G4n) return;
  float f0 = 0.f, f1 = 0.f, b0 = 0.f, b1 = 0.f;
  for (int e = 0; e < En; ++e) {
    const float w0 = W_embed[e * 2 + 0];
    const float w1 = W_embed[e * 2 + 1];
    const float wf = Wih_f[gidx * En + e];
    const float wb = Wih_b[gidx * En + e];
    f0 = fmaf(wf, w0, f0); f1 = fmaf(wf, w1, f1);
    b0 = fmaf(wb, w0, b0); b1 = fmaf(wb, w1, b1);
  }
  weff_f[gidx * 2 + 0] = f0; weff_f[gidx * 2 + 1] = f1;
  weff_b[gidx * 2 + 0] = b0; weff_b[gidx * 2 + 1] = b1;
}

// ---------------------------------------------------------------------------
template<typename ET>
__global__ __launch_bounds__(256) void enc_lstm(const float* gf, const float* gb,
                                                float* cf, float* cb,
                                                float* hf, float* hb,
                                                ET* Enc, int t) {
  const int idx = blockIdx.x * 256 + threadIdx.x;   // B*H*2
  const int dir = idx >= Bn * Hn;
  const int r = idx - dir * Bn * Hn;
  const int b = r >> 8;
  const int h = r & 255;
  const float* g = dir ? gb : gf;
  float* c = dir ? cb : cf;
  float* hbuf = dir ? hb : hf;
  const float gi  = g[b * G4n + h];
  const float gfo = g[b * G4n + Hn + h];
  const float gg  = g[b * G4n + 2 * Hn + h];
  const float go  = g[b * G4n + 3 * Hn + h];
  const float cold = c[b * Hn + h];
  const float cn = sigmoidf(gfo) * cold + sigmoidf(gi) * tanhf(gg);
  const float hn = sigmoidf(go) * tanhf(cn);
  c[b * Hn + h] = cn;
  hbuf[b * Hn + h] = hn;
  const int tt = dir ? (Tn - 1 - t) : t;
  Enc[(size_t)b * Tn * D2n + (size_t)tt * D2n + dir * Hn + h] = cvt_from_f<ET>(hn);
}

__global__ __launch_bounds__(256) void dec_lstm(const float* gf, const float* gb,
                                                float* cf, float* cb, float* dec_out) {
  const int idx = blockIdx.x * 256 + threadIdx.x;   // B*H*2
  const int dir = idx >= Bn * Hn;
  const int r = idx - dir * Bn * Hn;
  const int b = r >> 8;
  const int h = r & 255;
  const float* g = dir ? gb : gf;
  float* c = dir ? cb : cf;
  const float gi  = g[b * G4n + h];
  const float gfo = g[b * G4n + Hn + h];
  const float gg  = g[b * G4n + 2 * Hn + h];
  const float go  = g[b * G4n + 3 * Hn + h];
  const float cold = c[b * Hn + h];
  const float cn = sigmoidf(gfo) * cold + sigmoidf(gi) * tanhf(gg);
  const float hn = sigmoidf(go) * tanhf(cn);
  c[b * Hn + h] = cn;
  dec_out[(size_t)b * D2n + dir * Hn + h] = hn;
}

// ---------------------------------------------------------------------------
// one wave per (attention, b, j): s = sum_k tanh(ref[b,j,k] + q[b,k]) * v[k]
template<typename RT>
__device__ __forceinline__ float att_row(const RT* rrow, const float* qrow,
                                         const float* vp, int lane) {
  float acc = 0.f;
#pragma unroll
  for (int i = 0; i < 2; ++i) {
    const int e = (i * 64 + lane) * 4;
    const float4 rr = load4<RT>(rrow + e);
    const float4 qq = *(const float4*)&qrow[e];
    const float4 vv = *(const float4*)&vp[e];
    acc = fmaf(tanhf(rr.x + qq.x), vv.x, acc);
    acc = fmaf(tanhf(rr.y + qq.y), vv.y, acc);
    acc = fmaf(tanhf(rr.z + qq.z), vv.z, acc);
    acc = fmaf(tanhf(rr.w + qq.w), vv.w, acc);
  }
  return acc;
}

template<typename RT1, typename RT2>
__global__ __launch_bounds__(256) void att_kernel(const RT1* ref1, const float* q1,
                                                  const float* v1, float* s1,
                                                  const RT2* ref2, const float* q2,
                                                  const float* v2, float* s2) {
  const int gwid = (blockIdx.x * 256 + threadIdx.x) >> 6;
  const int lane = threadIdx.x & 63;
  const int which = gwid >= Bn * Tn;
  const int r = gwid - which * Bn * Tn;
  const int b = r / Tn;
  const int j = r - b * Tn;
  float acc;
  if (!which)
    acc = att_row<RT1>(ref1 + (size_t)(b * Tn + j) * D2n, q1 + (size_t)b * D2n, v1, lane);
  else
    acc = att_row<RT2>(ref2 + (size_t)(b * Tn + j) * D2n, q2 + (size_t)b * D2n, v2, lane);
#pragma unroll
  for (int off = 32; off > 0; off >>= 1) acc += __shfl_xor(acc, off, 64);
  if (lane == 0) (which ? s2 : s1)[b * Tn + j] = acc;
}

// ---------------------------------------------------------------------------
// one block per b: softmax(u)->aw, argmax/lse over penalized ow, ce, played,
// x_new = sum_j aw[j] * Enc[b,j,:]
template<typename ET>
__global__ __launch_bounds__(256) void step_kernel(const float* s1, const float* s2,
                                                   const ET* Enc, float* played,
                                                   float* x_new, float* loss_out,
                                                   const int* test_roads, int t) {
  const int b = blockIdx.x;
  const int tid = threadIdx.x;
  __shared__ float aw[Tn];
  __shared__ float red[256];
  __shared__ int redi[256];

  const float uval = (tid < Tn) ? s2[b * Tn + tid] : -INFINITY;
  const float owval = (tid < Tn) ? (s1[b * Tn + tid] - PENf * played[b * Tn + tid])
                                 : -INFINITY;
  // softmax over u
  red[tid] = uval; __syncthreads();
  for (int s = 128; s > 0; s >>= 1) {
    if (tid < s) red[tid] = fmaxf(red[tid], red[tid + s]);
    __syncthreads();
  }
  const float umax = red[0]; __syncthreads();
  const float e = (tid < Tn) ? expf(uval - umax) : 0.f;
  red[tid] = e; __syncthreads();
  for (int s = 128; s > 0; s >>= 1) {
    if (tid < s) red[tid] += red[tid + s];
    __syncthreads();
  }
  const float usum = red[0]; __syncthreads();
  if (tid < Tn) aw[tid] = e / usum;

  // argmax over ow (first-index tie-break, matches jnp.argmax)
  red[tid] = owval; redi[tid] = (tid < Tn) ? tid : 0x7fffffff; __syncthreads();
  for (int s = 128; s > 0; s >>= 1) {
    if (tid < s) {
      const float ov = red[tid + s]; const int oi = redi[tid + s];
      if (ov > red[tid] || (ov == red[tid] && oi < redi[tid])) {
        red[tid] = ov; redi[tid] = oi;
      }
    }
    __syncthreads();
  }
  const float omax = red[0]; const int sel = redi[0]; __syncthreads();

  // logsumexp over ow
  const float eo = (tid < Tn) ? expf(owval - omax) : 0.f;
  red[tid] = eo; __syncthreads();
  for (int s = 128; s > 0; s >>= 1) {
    if (tid < s) red[tid] += red[tid + s];
    __syncthreads();
  }
  if (tid == 0) {
    const float lse = omax + logf(red[0]);
    const int tgt = test_roads[b * Tn + t];
    const float owt = s1[b * Tn + tgt] - PENf * played[b * Tn + tgt];
    loss_out[b] += lse - owt;
    played[b * Tn + sel] += 1.f;
  }
  __syncthreads();

  // x_new[b,k] = sum_j aw[j] * Enc[b,j,k]
  const ET* Eb = Enc + (size_t)b * Tn * D2n;
  for (int k = tid; k < D2n; k += 256) {
    float acc = 0.f;
    for (int j = 0; j < Tn; ++j)
      acc = fmaf(aw[j], cvt_to_f<ET>(Eb[(size_t)j * D2n + k]), acc);
    x_new[(size_t)b * D2n + k] = acc;
  }
}

// ---------------------------------------------------------------------------
template<typename ET, typename RT1, typename RT2>
static void run_all(void* const* d_in, void* d_out, char* ws, size_t footBytes,
                    hipStream_t stream) {
  const float* inputs     = (const float*)d_in[0];
  const int*   test_roads = (const int*)d_in[1];
  const float* W_embed    = (const float*)d_in[2];
  const float* enc_Wih_f  = (const float*)d_in[3];
  const float* enc_Whh_f  = (const float*)d_in[4];
  const float* enc_b_f    = (const float*)d_in[5];
  const float* enc_Wih_b  = (const float*)d_in[6];
  const float* enc_Whh_b  = (const float*)d_in[7];
  const float* enc_b_b    = (const float*)d_in[8];
  const float* dec_Wih_f  = (const float*)d_in[9];
  const float* dec_Whh_f  = (const float*)d_in[10];
  const float* dec_b_f    = (const float*)d_in[11];
  const float* dec_Wih_b  = (const float*)d_in[12];
  const float* dec_Whh_b  = (const float*)d_in[13];
  const float* dec_b_b    = (const float*)d_in[14];
  const float* W_ref      = (const float*)d_in[15];
  const float* W_q        = (const float*)d_in[16];
  const float* v          = (const float*)d_in[17];
  const float* W_ref2     = (const float*)d_in[18];
  const float* W_q2       = (const float*)d_in[19];
  const float* v2         = (const float*)d_in[20];

  char* ws0 = ws;
  ET*  Enc  = (ET*)ws;  ws += BIGN * sizeof(ET);
  RT1* ref1 = (RT1*)ws; ws += BIGN * sizeof(RT1);
  RT2* ref2 = (RT2*)ws; ws += BIGN * sizeof(RT2);
  float* p = (float*)ws;
  float* gates_f = p; p += (size_t)Bn * G4n;
  float* gates_b = p; p += (size_t)Bn * G4n;
  float* xb0     = p; p += (size_t)Bn * D2n;
  float* xb1     = p; p += (size_t)Bn * D2n;
  float* dec_out = p; p += (size_t)Bn * D2n;
  float* qb      = p; p += (size_t)Bn * D2n;
  float* q2b     = p; p += (size_t)Bn * D2n;
  float* s1      = p; p += (size_t)Bn * Tn;
  float* s2      = p; p += (size_t)Bn * Tn;
  float* played  = p; p += (size_t)Bn * Tn;
  float* h_f     = p; p += (size_t)Bn * Hn;
  float* c_f     = p; p += (size_t)Bn * Hn;
  float* h_b     = p; p += (size_t)Bn * Hn;
  float* c_b     = p; p += (size_t)Bn * Hn;
  float* weff_f  = p; p += (size_t)G4n * 2;
  float* weff_b  = p; p += (size_t)G4n * 2;

  float* loss = (float*)d_out;

  // zero everything we use (refs are accumulated, h/c/played/x0 must start 0)
  hipMemsetAsync(ws0, 0, footBytes, stream);
  hipMemsetAsync(loss, 0, Bn * sizeof(float), stream);

  weff_kernel<<<G4n / 256, 256, 0, stream>>>(enc_Wih_f, enc_Wih_b, W_embed,
                                             weff_f, weff_b);

  // helper to build the 4 ref-accumulation sets for h_f (pos pf) / h_b (pos pb)
  auto launch_ref4 = [&](int pf, int pb) {
    GemmSetT<RT1> r1f = { h_f, W_ref,        Hn, Hn, D2n, nullptr, nullptr, 0, 0, 0,
                          nullptr, ref1 + (size_t)pf * D2n, Tn * D2n, 1 };
    GemmSetT<RT1> r1b = { h_b, W_ref + Hn,   Hn, Hn, D2n, nullptr, nullptr, 0, 0, 0,
                          nullptr, ref1 + (size_t)pb * D2n, Tn * D2n, 1 };
    GemmSetT<RT2> r2f = { h_f, W_ref2,       Hn, Hn, D2n, nullptr, nullptr, 0, 0, 0,
                          nullptr, ref2 + (size_t)pf * D2n, Tn * D2n, 1 };
    GemmSetT<RT2> r2b = { h_b, W_ref2 + Hn,  Hn, Hn, D2n, nullptr, nullptr, 0, 0, 0,
                          nullptr, ref2 + (size_t)pb * D2n, Tn * D2n, 1 };
    gemm4_kernel<RT1, RT2><<<dim3(D2n / 64, Bn / 64, 4), 256, GEMM_SMEM, stream>>>(
        r1f, r1b, r2f, r2b);
  };

  // ---- encoder: 100 sequential steps, both directions per launch ----
  for (int t = 0; t < Tn; ++t) {
    GemmSetT<float> gf = { h_f, enc_Whh_f, Hn, Hn, Hn,
                           inputs + t * 2, weff_f, 2, Tn * 2, 2,
                           enc_b_f, gates_f, G4n, 0 };
    GemmSetT<float> gb = { h_b, enc_Whh_b, Hn, Hn, Hn,
                           inputs + (Tn - 1 - t) * 2, weff_b, 2, Tn * 2, 2,
                           enc_b_b, gates_b, G4n, 0 };
    gemm2_kernel<float><<<dim3(G4n / 64, Bn / 64, 2), 256, GEMM_SMEM, stream>>>(gf, gb);
    // accumulate refs from the fp32 h of the PREVIOUS iteration (still live)
    if (t > 0) launch_ref4(t - 1, Tn - t);
    enc_lstm<ET><<<(Bn * Hn * 2) / 256, 256, 0, stream>>>(gates_f, gates_b,
                                                          c_f, c_b, h_f, h_b, Enc, t);
  }
  launch_ref4(Tn - 1, 0);   // final h_f (pos 99) and h_b (pos 0)

  // ---- decoder: 100 sequential steps ----
  float* xbuf[2] = { xb0, xb1 };
  for (int t = 0; t < Tn; ++t) {
    float* xc = xbuf[t & 1];
    float* xn = xbuf[(t + 1) & 1];
    const float* hf_src = (t == 0) ? h_f : dec_out;
    const float* hb_src = (t == 0) ? h_b : (dec_out + Hn);
    const int h_lda = (t == 0) ? Hn : D2n;

    GemmSetT<float> cf = { xc, dec_Wih_f, D2n, D2n, D2n,
                           hf_src, dec_Whh_f, Hn, h_lda, Hn,
                           dec_b_f, gates_f, G4n, 0 };
    GemmSetT<float> cb = { xc, dec_Wih_b, D2n, D2n, D2n,
                           hb_src, dec_Whh_b, Hn, h_lda, Hn,
                           dec_b_b, gates_b, G4n, 0 };
    gemm2_kernel<float><<<dim3(G4n / 64, Bn / 64, 2), 256, GEMM_SMEM, stream>>>(cf, cb);

    dec_lstm<<<(Bn * Hn * 2) / 256, 256, 0, stream>>>(gates_f, gates_b,
                                                      c_f, c_b, dec_out);

    GemmSetT<float> gq  = { dec_out, W_q,  D2n, D2n, D2n,
                            nullptr, nullptr, 0, 0, 0, nullptr, qb,  D2n, 0 };
    GemmSetT<float> gq2 = { xc,      W_q2, D2n, D2n, D2n,
                            nullptr, nullptr, 0, 0, 0, nullptr, q2b, D2n, 0 };
    gemm2_kernel<float><<<dim3(D2n / 64, Bn / 64, 2), 256, GEMM_SMEM, stream>>>(gq, gq2);

    att_kernel<RT1, RT2><<<(2 * Bn * Tn) / 4, 256, 0, stream>>>(ref1, qb, v, s1,
                                                                ref2, q2b, v2, s2);

    step_kernel<ET><<<Bn, 256, 0, stream>>>(s1, s2, Enc, played, xn, loss,
                                            test_roads, t);
  }
}

// ---------------------------------------------------------------------------
extern "C" void kernel_launch(void* const* d_in, const int* in_sizes, int n_in,
                              void* d_out, int out_size, void* d_ws, size_t ws_size,
                              hipStream_t stream) {
  (void)in_sizes; (void)n_in; (void)out_size;
  char* ws = (char*)d_ws;
  const size_t szA = 3 * BIGN * 4 + SMALL_BYTES;               // ~326.7 MB all f32
  const size_t szB = 2 * BIGN * 4 + BIGN * 2 + SMALL_BYTES;    // ~274.3 MB Enc f16
  const size_t szC = BIGN * 4 + 2 * BIGN * 2 + SMALL_BYTES;    // ~221.9 MB +ref2 f16
  const size_t szD = 3 * BIGN * 2 + SMALL_BYTES;               // ~169.5 MB all f16
  if (ws_size >= szA)      run_all<float,  float,  float >(d_in, d_out, ws, szA, stream);
  else if (ws_size >= szB) run_all<__half, float,  float >(d_in, d_out, ws, szB, stream);
  else if (ws_size >= szC) run_all<__half, float,  __half>(d_in, d_out, ws, szC, stream);
  else                     run_all<__half, __half, __half>(d_in, d_out, ws, szD, stream);
}

// Round 4
// 24840.523 us; speedup vs baseline: 1.5507x; 1.5507x over previous
//
#include <hip/hip_runtime.h>
#include <hip/hip_fp16.h>
#include <math.h>

namespace {
constexpr int Bn  = 512;
constexpr int Tn  = 100;
constexpr int Hn  = 256;
constexpr int En  = 256;
constexpr int D2n = 512;
constexpr int G4n = 1024;
constexpr float PENf = 1e6f;
constexpr size_t BIGN = (size_t)Bn * Tn * D2n;   // 26,214,400 elements
constexpr size_t SMALL_BYTES =
    ((size_t)2 * Bn * G4n + 5 * Bn * D2n + 3 * Bn * Tn + 4 * Bn * Hn + 4 * G4n) * 4;
}

using short8  = __attribute__((ext_vector_type(8))) short;
using floatx4 = __attribute__((ext_vector_type(4))) float;

// ---- type conversion helpers ----------------------------------------------
template<typename T> __device__ __forceinline__ float cvt_to_f(T x);
template<> __device__ __forceinline__ float cvt_to_f<float>(float x) { return x; }
template<> __device__ __forceinline__ float cvt_to_f<__half>(__half x) {
  return __half2float(x);
}

template<typename T> __device__ __forceinline__ T cvt_from_f(float x);
template<> __device__ __forceinline__ float cvt_from_f<float>(float x) { return x; }
template<> __device__ __forceinline__ __half cvt_from_f<__half>(float x) {
  return __float2half(x);   // round-to-nearest-even
}

__device__ __forceinline__ float h2f_bits(unsigned short b) {
  __half_raw r; r.x = b; return __half2float(__half(r));
}

template<typename T> __device__ __forceinline__ float4 load4(const T* p);
template<> __device__ __forceinline__ float4 load4<float>(const float* p) {
  return *(const float4*)p;
}
template<> __device__ __forceinline__ float4 load4<__half>(const __half* p) {
  const ushort4 u = *(const ushort4*)p;   // 8B-aligned at all call sites
  float4 r;
  r.x = h2f_bits(u.x); r.y = h2f_bits(u.y);
  r.z = h2f_bits(u.z); r.w = h2f_bits(u.w);
  return r;
}

__device__ __forceinline__ float sigmoidf(float x) {
  return 1.0f / (1.0f + expf(-x));
}

// fp32 -> (hi bf16 by truncation, lo bf16 round-half of residual)
__device__ __forceinline__ void split2(float x, short& h, short& l) {
  const unsigned u  = __float_as_uint(x);
  const unsigned hu = u & 0xffff0000u;
  h = (short)(hu >> 16);
  const float r = x - __uint_as_float(hu);
  l = (short)((__float_as_uint(r) + 0x8000u) >> 16);
}

__device__ __forceinline__ void store4split(const float4 v, short* hp, short* lp) {
  short h0, h1, h2, h3, l0, l1, l2, l3;
  split2(v.x, h0, l0); split2(v.y, h1, l1);
  split2(v.z, h2, l2); split2(v.w, h3, l3);
  *(short4*)hp = make_short4(h0, h1, h2, h3);
  *(short4*)lp = make_short4(l0, l1, l2, l3);
}

// ---------------------------------------------------------------------------
// Split-bf16 MFMA GEMM:
//   C[m,n] (+)= bias[n] + sum_seg sum_k A[m,k]*B[n,k] + X[m,0]*W2[n,0]+X[m,1]*W2[n,1]
// A,B fp32 in global, split to hi/lo bf16 at staging; fp32 MFMA accumulate.
// M,N multiples of 64; every K multiple of 32.
// ---------------------------------------------------------------------------
template<typename CT>
struct GemmSetT {
  const float* A1; const float* B1; int K1; int lda1; int ldb1;
  const float* A2; const float* B2; int K2; int lda2; int ldb2;
  const float* X; int ldx; const float* W2;     // optional rank-2 term (K==2)
  const float* bias; CT* C; int ldc; int acc;
};

template<typename CT>
__device__ __forceinline__ void gemm_body(const GemmSetT<CT>& g, short* smem,
                                          int m0, int n0) {
  short* Ahi = smem;            // [4 kgroups][64 rows][8]  (2048 bf16 = 4KB)
  short* Alo = smem + 2048;
  short* Bhi = smem + 4096;
  short* Blo = smem + 6144;
  const int tid  = threadIdx.x;
  const int lane = tid & 63;
  const int wave = tid >> 6;
  const int qm   = lane & 15;   // row within 16
  const int quad = lane >> 4;   // k-group

  floatx4 acc[4];
#pragma unroll
  for (int nt = 0; nt < 4; ++nt) acc[nt] = (floatx4){0.f, 0.f, 0.f, 0.f};

  for (int seg = 0; seg < 2; ++seg) {
    const float* A  = seg ? g.A2 : g.A1;
    const float* Bm = seg ? g.B2 : g.B1;
    const int K   = seg ? g.K2 : g.K1;
    const int lda = seg ? g.lda2 : g.lda1;
    const int ldb = seg ? g.ldb2 : g.ldb1;
    if (K <= 0) continue;
    for (int k0 = 0; k0 < K; k0 += 32) {
      __syncthreads();
      // stage 64x32 A and B tiles: 512 float4 each, 2 per thread per matrix
#pragma unroll
      for (int h = 0; h < 2; ++h) {
        const int idx = tid + h * 256;
        const int r  = idx >> 3;
        const int c4 = idx & 7;
        const int gq = c4 >> 1;
        const int j0 = (c4 & 1) * 4;
        const int base = gq * 512 + r * 8 + j0;
        const float4 av = *(const float4*)(A + (size_t)(m0 + r) * lda + k0 + c4 * 4);
        store4split(av, &Ahi[base], &Alo[base]);
        const float4 bv = *(const float4*)(Bm + (size_t)(n0 + r) * ldb + k0 + c4 * 4);
        store4split(bv, &Bhi[base], &Blo[base]);
      }
      __syncthreads();
      const int abase = quad * 512 + (wave * 16 + qm) * 8;
      const short8 ah = *(const short8*)&Ahi[abase];
      const short8 al = *(const short8*)&Alo[abase];
#pragma unroll
      for (int nt = 0; nt < 4; ++nt) {
        const int bbase = quad * 512 + (nt * 16 + qm) * 8;
        const short8 bh = *(const short8*)&Bhi[bbase];
        const short8 bl = *(const short8*)&Blo[bbase];
        acc[nt] = __builtin_amdgcn_mfma_f32_16x16x32_bf16(ah, bh, acc[nt], 0, 0, 0);
        acc[nt] = __builtin_amdgcn_mfma_f32_16x16x32_bf16(ah, bl, acc[nt], 0, 0, 0);
        acc[nt] = __builtin_amdgcn_mfma_f32_16x16x32_bf16(al, bh, acc[nt], 0, 0, 0);
      }
    }
  }

  // epilogue: C/D layout col = lane&15, row = quad*4 + reg
  float xa[4], xb[4];
  if (g.X) {
#pragma unroll
    for (int r2 = 0; r2 < 4; ++r2) {
      const int m = m0 + wave * 16 + quad * 4 + r2;
      xa[r2] = g.X[(size_t)m * g.ldx];
      xb[r2] = g.X[(size_t)m * g.ldx + 1];
    }
  }
#pragma unroll
  for (int nt = 0; nt < 4; ++nt) {
    const int n = n0 + nt * 16 + qm;
    const float bn  = g.bias ? g.bias[n] : 0.f;
    float w20 = 0.f, w21 = 0.f;
    if (g.X) { w20 = g.W2[n * 2]; w21 = g.W2[n * 2 + 1]; }
#pragma unroll
    for (int r2 = 0; r2 < 4; ++r2) {
      const int m = m0 + wave * 16 + quad * 4 + r2;
      float o = acc[nt][r2] + bn;
      if (g.X) o = fmaf(xa[r2], w20, fmaf(xb[r2], w21, o));
      CT* cp = &g.C[(size_t)m * g.ldc + n];
      if (g.acc) o += cvt_to_f<CT>(*cp);
      *cp = cvt_from_f<CT>(o);
    }
  }
}

template<typename CT>
__global__ __launch_bounds__(256) void gemm2_kernel(GemmSetT<CT> s0, GemmSetT<CT> s1) {
  __shared__ __align__(16) short smem[8192];
  gemm_body<CT>(blockIdx.z ? s1 : s0, smem, blockIdx.y * 64, blockIdx.x * 64);
}

// 4 sets: 0,1 write CT1 (ref1 halves), 2,3 write CT2 (ref2 halves)
template<typename CT1, typename CT2>
__global__ __launch_bounds__(256) void gemm4_kernel(GemmSetT<CT1> s0, GemmSetT<CT1> s1,
                                                    GemmSetT<CT2> s2, GemmSetT<CT2> s3) {
  __shared__ __align__(16) short smem[8192];
  const int m0 = blockIdx.y * 64, n0 = blockIdx.x * 64;
  if (blockIdx.z < 2) gemm_body<CT1>(blockIdx.z ? s1 : s0, smem, m0, n0);
  else                gemm_body<CT2>(blockIdx.z == 3 ? s3 : s2, smem, m0, n0);
}

// ---------------------------------------------------------------------------
// Weff = Wih @ W_embed : [1024,2] per direction
__global__ void weff_kernel(const float* Wih_f, const float* Wih_b,
                            const float* W_embed, float* weff_f, float* weff_b) {
  const int gidx = blockIdx.x * 256 + threadIdx.x;
  if (gidx >= G4n) return;
  float f0 = 0.f, f1 = 0.f, b0 = 0.f, b1 = 0.f;
  for (int e = 0; e < En; ++e) {
    const float w0 = W_embed[e * 2 + 0];
    const float w1 = W_embed[e * 2 + 1];
    const float wf = Wih_f[gidx * En + e];
    const float wb = Wih_b[gidx * En + e];
    f0 = fmaf(wf, w0, f0); f1 = fmaf(wf, w1, f1);
    b0 = fmaf(wb, w0, b0); b1 = fmaf(wb, w1, b1);
  }
  weff_f[gidx * 2 + 0] = f0; weff_f[gidx * 2 + 1] = f1;
  weff_b[gidx * 2 + 0] = b0; weff_b[gidx * 2 + 1] = b1;
}

// ---------------------------------------------------------------------------
template<typename ET>
__global__ __launch_bounds__(256) void enc_lstm(const float* gf, const float* gb,
                                                float* cf, float* cb,
                                                float* hf, float* hb,
                                                ET* Enc, int t) {
  const int idx = blockIdx.x * 256 + threadIdx.x;   // B*H*2
  const int dir = idx >= Bn * Hn;
  const int r = idx - dir * Bn * Hn;
  const int b = r >> 8;
  const int h = r & 255;
  const float* g = dir ? gb : gf;
  float* c = dir ? cb : cf;
  float* hbuf = dir ? hb : hf;
  const float gi  = g[b * G4n + h];
  const float gfo = g[b * G4n + Hn + h];
  const float gg  = g[b * G4n + 2 * Hn + h];
  const float go  = g[b * G4n + 3 * Hn + h];
  const float cold = c[b * Hn + h];
  const float cn = sigmoidf(gfo) * cold + sigmoidf(gi) * tanhf(gg);
  const float hn = sigmoidf(go) * tanhf(cn);
  c[b * Hn + h] = cn;
  hbuf[b * Hn + h] = hn;
  const int tt = dir ? (Tn - 1 - t) : t;
  Enc[(size_t)b * Tn * D2n + (size_t)tt * D2n + dir * Hn + h] = cvt_from_f<ET>(hn);
}

__global__ __launch_bounds__(256) void dec_lstm(const float* gf, const float* gb,
                                                float* cf, float* cb, float* dec_out) {
  const int idx = blockIdx.x * 256 + threadIdx.x;   // B*H*2
  const int dir = idx >= Bn * Hn;
  const int r = idx - dir * Bn * Hn;
  const int b = r >> 8;
  const int h = r & 255;
  const float* g = dir ? gb : gf;
  float* c = dir ? cb : cf;
  const float gi  = g[b * G4n + h];
  const float gfo = g[b * G4n + Hn + h];
  const float gg  = g[b * G4n + 2 * Hn + h];
  const float go  = g[b * G4n + 3 * Hn + h];
  const float cold = c[b * Hn + h];
  const float cn = sigmoidf(gfo) * cold + sigmoidf(gi) * tanhf(gg);
  const float hn = sigmoidf(go) * tanhf(cn);
  c[b * Hn + h] = cn;
  dec_out[(size_t)b * D2n + dir * Hn + h] = hn;
}

// ---------------------------------------------------------------------------
// one wave per (attention, b, j): s = sum_k tanh(ref[b,j,k] + q[b,k]) * v[k]
template<typename RT>
__device__ __forceinline__ float att_row(const RT* rrow, const float* qrow,
                                         const float* vp, int lane) {
  float acc = 0.f;
#pragma unroll
  for (int i = 0; i < 2; ++i) {
    const int e = (i * 64 + lane) * 4;
    const float4 rr = load4<RT>(rrow + e);
    const float4 qq = *(const float4*)&qrow[e];
    const float4 vv = *(const float4*)&vp[e];
    acc = fmaf(tanhf(rr.x + qq.x), vv.x, acc);
    acc = fmaf(tanhf(rr.y + qq.y), vv.y, acc);
    acc = fmaf(tanhf(rr.z + qq.z), vv.z, acc);
    acc = fmaf(tanhf(rr.w + qq.w), vv.w, acc);
  }
  return acc;
}

template<typename RT1, typename RT2>
__global__ __launch_bounds__(256) void att_kernel(const RT1* ref1, const float* q1,
                                                  const float* v1, float* s1,
                                                  const RT2* ref2, const float* q2,
                                                  const float* v2, float* s2) {
  const int gwid = (blockIdx.x * 256 + threadIdx.x) >> 6;
  const int lane = threadIdx.x & 63;
  const int which = gwid >= Bn * Tn;
  const int r = gwid - which * Bn * Tn;
  const int b = r / Tn;
  const int j = r - b * Tn;
  float acc;
  if (!which)
    acc = att_row<RT1>(ref1 + (size_t)(b * Tn + j) * D2n, q1 + (size_t)b * D2n, v1, lane);
  else
    acc = att_row<RT2>(ref2 + (size_t)(b * Tn + j) * D2n, q2 + (size_t)b * D2n, v2, lane);
#pragma unroll
  for (int off = 32; off > 0; off >>= 1) acc += __shfl_xor(acc, off, 64);
  if (lane == 0) (which ? s2 : s1)[b * Tn + j] = acc;
}

// ---------------------------------------------------------------------------
// one block per b: softmax(u)->aw, argmax/lse over penalized ow, ce, played,
// x_new = sum_j aw[j] * Enc[b,j,:]
template<typename ET>
__global__ __launch_bounds__(256) void step_kernel(const float* s1, const float* s2,
                                                   const ET* Enc, float* played,
                                                   float* x_new, float* loss_out,
                                                   const int* test_roads, int t) {
  const int b = blockIdx.x;
  const int tid = threadIdx.x;
  __shared__ float aw[Tn];
  __shared__ float red[256];
  __shared__ int redi[256];

  const float uval = (tid < Tn) ? s2[b * Tn + tid] : -INFINITY;
  const float owval = (tid < Tn) ? (s1[b * Tn + tid] - PENf * played[b * Tn + tid])
                                 : -INFINITY;
  // softmax over u
  red[tid] = uval; __syncthreads();
  for (int s = 128; s > 0; s >>= 1) {
    if (tid < s) red[tid] = fmaxf(red[tid], red[tid + s]);
    __syncthreads();
  }
  const float umax = red[0]; __syncthreads();
  const float e = (tid < Tn) ? expf(uval - umax) : 0.f;
  red[tid] = e; __syncthreads();
  for (int s = 128; s > 0; s >>= 1) {
    if (tid < s) red[tid] += red[tid + s];
    __syncthreads();
  }
  const float usum = red[0]; __syncthreads();
  if (tid < Tn) aw[tid] = e / usum;

  // argmax over ow (first-index tie-break, matches jnp.argmax)
  red[tid] = owval; redi[tid] = (tid < Tn) ? tid : 0x7fffffff; __syncthreads();
  for (int s = 128; s > 0; s >>= 1) {
    if (tid < s) {
      const float ov = red[tid + s]; const int oi = redi[tid + s];
      if (ov > red[tid] || (ov == red[tid] && oi < redi[tid])) {
        red[tid] = ov; redi[tid] = oi;
      }
    }
    __syncthreads();
  }
  const float omax = red[0]; const int sel = redi[0]; __syncthreads();

  // logsumexp over ow
  const float eo = (tid < Tn) ? expf(owval - omax) : 0.f;
  red[tid] = eo; __syncthreads();
  for (int s = 128; s > 0; s >>= 1) {
    if (tid < s) red[tid] += red[tid + s];
    __syncthreads();
  }
  if (tid == 0) {
    const float lse = omax + logf(red[0]);
    const int tgt = test_roads[b * Tn + t];
    const float owt = s1[b * Tn + tgt] - PENf * played[b * Tn + tgt];
    loss_out[b] += lse - owt;
    played[b * Tn + sel] += 1.f;
  }
  __syncthreads();

  // x_new[b,k] = sum_j aw[j] * Enc[b,j,k]
  const ET* Eb = Enc + (size_t)b * Tn * D2n;
  for (int k = tid; k < D2n; k += 256) {
    float acc = 0.f;
    for (int j = 0; j < Tn; ++j)
      acc = fmaf(aw[j], cvt_to_f<ET>(Eb[(size_t)j * D2n + k]), acc);
    x_new[(size_t)b * D2n + k] = acc;
  }
}

// ---------------------------------------------------------------------------
template<typename ET, typename RT1, typename RT2>
static void run_all(void* const* d_in, void* d_out, char* ws, size_t footBytes,
                    hipStream_t stream) {
  const float* inputs     = (const float*)d_in[0];
  const int*   test_roads = (const int*)d_in[1];
  const float* W_embed    = (const float*)d_in[2];
  const float* enc_Wih_f  = (const float*)d_in[3];
  const float* enc_Whh_f  = (const float*)d_in[4];
  const float* enc_b_f    = (const float*)d_in[5];
  const float* enc_Wih_b  = (const float*)d_in[6];
  const float* enc_Whh_b  = (const float*)d_in[7];
  const float* enc_b_b    = (const float*)d_in[8];
  const float* dec_Wih_f  = (const float*)d_in[9];
  const float* dec_Whh_f  = (const float*)d_in[10];
  const float* dec_b_f    = (const float*)d_in[11];
  const float* dec_Wih_b  = (const float*)d_in[12];
  const float* dec_Whh_b  = (const float*)d_in[13];
  const float* dec_b_b    = (const float*)d_in[14];
  const float* W_ref      = (const float*)d_in[15];
  const float* W_q        = (const float*)d_in[16];
  const float* v          = (const float*)d_in[17];
  const float* W_ref2     = (const float*)d_in[18];
  const float* W_q2       = (const float*)d_in[19];
  const float* v2         = (const float*)d_in[20];

  char* ws0 = ws;
  ET*  Enc  = (ET*)ws;  ws += BIGN * sizeof(ET);
  RT1* ref1 = (RT1*)ws; ws += BIGN * sizeof(RT1);
  RT2* ref2 = (RT2*)ws; ws += BIGN * sizeof(RT2);
  float* p = (float*)ws;
  float* gates_f = p; p += (size_t)Bn * G4n;
  float* gates_b = p; p += (size_t)Bn * G4n;
  float* xb0     = p; p += (size_t)Bn * D2n;
  float* xb1     = p; p += (size_t)Bn * D2n;
  float* dec_out = p; p += (size_t)Bn * D2n;
  float* qb      = p; p += (size_t)Bn * D2n;
  float* q2b     = p; p += (size_t)Bn * D2n;
  float* s1      = p; p += (size_t)Bn * Tn;
  float* s2      = p; p += (size_t)Bn * Tn;
  float* played  = p; p += (size_t)Bn * Tn;
  float* h_f     = p; p += (size_t)Bn * Hn;
  float* c_f     = p; p += (size_t)Bn * Hn;
  float* h_b     = p; p += (size_t)Bn * Hn;
  float* c_b     = p; p += (size_t)Bn * Hn;
  float* weff_f  = p; p += (size_t)G4n * 2;
  float* weff_b  = p; p += (size_t)G4n * 2;

  float* loss = (float*)d_out;

  // zero everything we use (refs are accumulated, h/c/played/x0 must start 0)
  hipMemsetAsync(ws0, 0, footBytes, stream);
  hipMemsetAsync(loss, 0, Bn * sizeof(float), stream);

  weff_kernel<<<G4n / 256, 256, 0, stream>>>(enc_Wih_f, enc_Wih_b, W_embed,
                                             weff_f, weff_b);

  // helper to build the 4 ref-accumulation sets for h_f (pos pf) / h_b (pos pb)
  auto launch_ref4 = [&](int pf, int pb) {
    GemmSetT<RT1> r1f = { h_f, W_ref,       Hn, Hn, D2n, nullptr, nullptr, 0, 0, 0,
                          nullptr, 0, nullptr, nullptr, ref1 + (size_t)pf * D2n, Tn * D2n, 1 };
    GemmSetT<RT1> r1b = { h_b, W_ref + Hn,  Hn, Hn, D2n, nullptr, nullptr, 0, 0, 0,
                          nullptr, 0, nullptr, nullptr, ref1 + (size_t)pb * D2n, Tn * D2n, 1 };
    GemmSetT<RT2> r2f = { h_f, W_ref2,      Hn, Hn, D2n, nullptr, nullptr, 0, 0, 0,
                          nullptr, 0, nullptr, nullptr, ref2 + (size_t)pf * D2n, Tn * D2n, 1 };
    GemmSetT<RT2> r2b = { h_b, W_ref2 + Hn, Hn, Hn, D2n, nullptr, nullptr, 0, 0, 0,
                          nullptr, 0, nullptr, nullptr, ref2 + (size_t)pb * D2n, Tn * D2n, 1 };
    gemm4_kernel<RT1, RT2><<<dim3(D2n / 64, Bn / 64, 4), 256, 0, stream>>>(
        r1f, r1b, r2f, r2b);
  };

  // ---- encoder: 100 sequential steps, both directions per launch ----
  // K=2 embedding term folded into the GEMM epilogue as a rank-2 update.
  for (int t = 0; t < Tn; ++t) {
    GemmSetT<float> gf = { h_f, enc_Whh_f, Hn, Hn, Hn,
                           nullptr, nullptr, 0, 0, 0,
                           inputs + t * 2, Tn * 2, weff_f,
                           enc_b_f, gates_f, G4n, 0 };
    GemmSetT<float> gb = { h_b, enc_Whh_b, Hn, Hn, Hn,
                           nullptr, nullptr, 0, 0, 0,
                           inputs + (Tn - 1 - t) * 2, Tn * 2, weff_b,
                           enc_b_b, gates_b, G4n, 0 };
    gemm2_kernel<float><<<dim3(G4n / 64, Bn / 64, 2), 256, 0, stream>>>(gf, gb);
    // accumulate refs from the fp32 h of the PREVIOUS iteration (still live)
    if (t > 0) launch_ref4(t - 1, Tn - t);
    enc_lstm<ET><<<(Bn * Hn * 2) / 256, 256, 0, stream>>>(gates_f, gates_b,
                                                          c_f, c_b, h_f, h_b, Enc, t);
  }
  launch_ref4(Tn - 1, 0);   // final h_f (pos 99) and h_b (pos 0)

  // ---- decoder: 100 sequential steps ----
  float* xbuf[2] = { xb0, xb1 };
  for (int t = 0; t < Tn; ++t) {
    float* xc = xbuf[t & 1];
    float* xn = xbuf[(t + 1) & 1];
    const float* hf_src = (t == 0) ? h_f : dec_out;
    const float* hb_src = (t == 0) ? h_b : (dec_out + Hn);
    const int h_lda = (t == 0) ? Hn : D2n;

    GemmSetT<float> cf = { xc, dec_Wih_f, D2n, D2n, D2n,
                           hf_src, dec_Whh_f, Hn, h_lda, Hn,
                           nullptr, 0, nullptr,
                           dec_b_f, gates_f, G4n, 0 };
    GemmSetT<float> cb = { xc, dec_Wih_b, D2n, D2n, D2n,
                           hb_src, dec_Whh_b, Hn, h_lda, Hn,
                           nullptr, 0, nullptr,
                           dec_b_b, gates_b, G4n, 0 };
    gemm2_kernel<float><<<dim3(G4n / 64, Bn / 64, 2), 256, 0, stream>>>(cf, cb);

    dec_lstm<<<(Bn * Hn * 2) / 256, 256, 0, stream>>>(gates_f, gates_b,
                                                      c_f, c_b, dec_out);

    GemmSetT<float> gq  = { dec_out, W_q,  D2n, D2n, D2n,
                            nullptr, nullptr, 0, 0, 0,
                            nullptr, 0, nullptr, nullptr, qb,  D2n, 0 };
    GemmSetT<float> gq2 = { xc,      W_q2, D2n, D2n, D2n,
                            nullptr, nullptr, 0, 0, 0,
                            nullptr, 0, nullptr, nullptr, q2b, D2n, 0 };
    gemm2_kernel<float><<<dim3(D2n / 64, Bn / 64, 2), 256, 0, stream>>>(gq, gq2);

    att_kernel<RT1, RT2><<<(2 * Bn * Tn) / 4, 256, 0, stream>>>(ref1, qb, v, s1,
                                                                ref2, q2b, v2, s2);

    step_kernel<ET><<<Bn, 256, 0, stream>>>(s1, s2, Enc, played, xn, loss,
                                            test_roads, t);
  }
}

// ---------------------------------------------------------------------------
extern "C" void kernel_launch(void* const* d_in, const int* in_sizes, int n_in,
                              void* d_out, int out_size, void* d_ws, size_t ws_size,
                              hipStream_t stream) {
  (void)in_sizes; (void)n_in; (void)out_size;
  char* ws = (char*)d_ws;
  const size_t szA = 3 * BIGN * 4 + SMALL_BYTES;               // ~326.7 MB all f32
  const size_t szB = 2 * BIGN * 4 + BIGN * 2 + SMALL_BYTES;    // ~274.3 MB Enc f16
  const size_t szC = BIGN * 4 + 2 * BIGN * 2 + SMALL_BYTES;    // ~221.9 MB +ref2 f16
  const size_t szD = 3 * BIGN * 2 + SMALL_BYTES;               // ~169.5 MB all f16
  if (ws_size >= szA)      run_all<float,  float,  float >(d_in, d_out, ws, szA, stream);
  else if (ws_size >= szB) run_all<__half, float,  float >(d_in, d_out, ws, szB, stream);
  else if (ws_size >= szC) run_all<__half, float,  __half>(d_in, d_out, ws, szC, stream);
  else                     run_all<__half, __half, __half>(d_in, d_out, ws, szD, stream);
}